// Round 12
// baseline (263.354 us; speedup 1.0000x reference)
//
#include <hip/hip_runtime.h>
#include <math.h>

#define N 1024
#define K 16
#define SENT 255
#define TAIL 128

// compiler fence + LDS drain (tail mode phase separation; DS pipe is in-order
// per wave, the fence stops compiler reordering of aliasing LDS ops)
#define WF() do { asm volatile("s_waitcnt lgkmcnt(0)" ::: "memory"); \
                  __builtin_amdgcn_sched_barrier(0); } while (0)

// (v2,f2) beats (v1,f1): larger value wins; tie -> smaller index
__device__ __forceinline__ bool better(float v2, int f2, float v1, int f1) {
    return (v2 > v1) || (v2 == v1 && f2 < f1);
}

template<int CTRL>
__device__ __forceinline__ void dpp_step(float& v, int& f) {
    int ovi = __builtin_amdgcn_update_dpp(0, __float_as_int(v), CTRL, 0xF, 0xF, true);
    int ofi = __builtin_amdgcn_update_dpp(0, f, CTRL, 0xF, 0xF, true);
    float ov = __int_as_float(ovi);
    if (better(ov, ofi, v, f)) { v = ov; f = ofi; }
}

// Full-wave argmax on (v,f); result broadcast to all lanes.
__device__ __forceinline__ void wave_argmax(float& v, int& f) {
    dpp_step<0xB1>(v, f);
    dpp_step<0x4E>(v, f);
    dpp_step<0x141>(v, f);
    dpp_step<0x140>(v, f);
    float v0 = __int_as_float(__builtin_amdgcn_readlane(__float_as_int(v), 0));
    int   f0 = __builtin_amdgcn_readlane(f, 0);
    float v1 = __int_as_float(__builtin_amdgcn_readlane(__float_as_int(v), 16));
    int   f1 = __builtin_amdgcn_readlane(f, 16);
    float v2 = __int_as_float(__builtin_amdgcn_readlane(__float_as_int(v), 32));
    int   f2 = __builtin_amdgcn_readlane(f, 32);
    float v3 = __int_as_float(__builtin_amdgcn_readlane(__float_as_int(v), 48));
    int   f3 = __builtin_amdgcn_readlane(f, 48);
    if (better(v1, f1, v0, f0)) { v0 = v1; f0 = f1; }
    if (better(v3, f3, v2, f2)) { v2 = v3; f2 = f3; }
    if (better(v2, f2, v0, f0)) { v0 = v2; f0 = f2; }
    v = v0; f = f0;
}

// top-K of one row of M (val desc, idx asc), one wave, coalesced.
__device__ __forceinline__ void topk_row_body(const float* __restrict__ M,
                                              unsigned short* __restrict__ listG,
                                              int row, int lane) {
    const float* rp = M + (size_t)row * N;
    float rv[16];
    #pragma unroll
    for (int k = 0; k < 16; ++k) rv[k] = rp[(k << 6) + lane];
    unsigned excl = 0;
    for (int pass = 0; pass < K; ++pass) {
        float best = -INFINITY; int bc = N;
        #pragma unroll
        for (int k = 0; k < 16; ++k) {
            int c = (k << 6) + lane;
            if (!((excl >> k) & 1u) && rv[k] > best) { best = rv[k]; bc = c; }
        }
        wave_argmax(best, bc);
        if (lane == (bc & 63)) excl |= 1u << (bc >> 6);
        if (lane == 0) listG[row * K + pass] = (unsigned short)bc;
    }
}

// ---------------------------------------------------------------------------
// K1: blocks 0..255 transpose 64x64 tiles C->CT; blocks 256..511 do row topK.
// ---------------------------------------------------------------------------
__global__ __launch_bounds__(256) void init_fused(const float* __restrict__ C,
                                                  float* __restrict__ CT,
                                                  unsigned short* __restrict__ rowListG) {
    const int b = blockIdx.x;
    if (b < 256) {
        __shared__ float T[64][65];
        const int t = threadIdx.x;
        const int tx = t & 63, ty = t >> 6;
        const int bi = b >> 4, bj = b & 15;
        #pragma unroll
        for (int k = 0; k < 16; ++k) {
            int r = (bi << 6) + ty + (k << 2);
            T[ty + (k << 2)][tx] = C[(size_t)r * N + (bj << 6) + tx];
        }
        __syncthreads();
        #pragma unroll
        for (int k = 0; k < 16; ++k) {
            int c = (bj << 6) + ty + (k << 2);
            CT[(size_t)c * N + (bi << 6) + tx] = T[tx][ty + (k << 2)];
        }
    } else {
        const int row = ((b - 256) << 2) + (threadIdx.x >> 6);
        topk_row_body(C, rowListG, row, threadIdx.x & 63);
    }
}

// ---------------------------------------------------------------------------
// K2: col topK = row topK of CT.
// ---------------------------------------------------------------------------
__global__ __launch_bounds__(256) void topk_kernel(const float* __restrict__ M,
                                                   unsigned short* __restrict__ listG) {
    int row  = (blockIdx.x * blockDim.x + threadIdx.x) >> 6;
    int lane = threadIdx.x & 63;
    if (row >= N) return;
    topk_row_body(M, listG, row, lane);
}

// ---------------------------------------------------------------------------
// Legacy col top-K via LDS tiles (mid-ws path only).
// ---------------------------------------------------------------------------
__global__ __launch_bounds__(1024) void topk_cols(const float* __restrict__ C,
                                                  unsigned short* __restrict__ colListG) {
    __shared__ float T[16][1025];
    const int t  = threadIdx.x;
    const int c0 = blockIdx.x << 4;
    const int cc = t & 15;
    const int tr = t >> 4;
    #pragma unroll
    for (int k = 0; k < 16; ++k) {
        int r = (k << 6) + tr;
        T[cc][r] = C[(size_t)r * N + c0 + cc];
    }
    __syncthreads();
    const int wave = t >> 6;
    const int lane = t & 63;
    const int c = c0 + wave;
    float rv[16];
    #pragma unroll
    for (int k = 0; k < 16; ++k) rv[k] = T[wave][(k << 6) + lane];
    unsigned excl = 0;
    for (int pass = 0; pass < K; ++pass) {
        float best = -INFINITY; int br = N;
        #pragma unroll
        for (int k = 0; k < 16; ++k) {
            int r = (k << 6) + lane;
            if (!((excl >> k) & 1u) && rv[k] > best) { best = rv[k]; br = r; }
        }
        wave_argmax(best, br);
        if (lane == (br & 63)) excl |= 1u << (br >> 6);
        if (lane == 0) colListG[c * K + pass] = (unsigned short)br;
    }
}

// ---------------------------------------------------------------------------
// K3 rounds: R10 structure + span-skip + wave-0 tail mode.
// ---------------------------------------------------------------------------
__global__ __launch_bounds__(1024) void rounds_fast(const float* __restrict__ C,
                                                    const float* __restrict__ CT,
                                                    const unsigned short* __restrict__ rowListG,
                                                    const unsigned short* __restrict__ colListG,
                                                    int* __restrict__ out,
                                                    int haveCT) {
    __shared__ unsigned short rowList[N * K];   // 32 KB
    __shared__ unsigned short colList[N * K];   // 32 KB
    __shared__ unsigned short rowHead[N];
    __shared__ unsigned short colHead[N];
    __shared__ unsigned char  rowPtr[N], colPtr[N];
    __shared__ unsigned aliveW[N / 32], usedW[N / 32];
    __shared__ unsigned short rowQ[N], colQ[N];
    __shared__ int rqn, cqn, matched;

    const int t = threadIdx.x;
    const int lane = t & 63;
    const int wave = t >> 6;

    #pragma unroll
    for (int i = 0; i < 2; ++i) {
        ((uint4*)rowList)[i * 1024 + t] = ((const uint4*)rowListG)[i * 1024 + t];
        ((uint4*)colList)[i * 1024 + t] = ((const uint4*)colListG)[i * 1024 + t];
    }
    rowPtr[t] = 0; colPtr[t] = 0;
    if (t < N / 32) { aliveW[t] = 0xFFFFFFFFu; usedW[t] = 0u; }
    if (t == 0) { matched = 0; rqn = 0; cqn = 0; }
    __syncthreads();
    rowHead[t] = rowList[t * K];
    colHead[t] = colList[t * K];
    __syncthreads();

    bool toTail = false;

    for (int round = 0; round < N + 8; ++round) {
        if (t == 0) { rqn = 0; cqn = 0; }
        // ---- phase 1: match mutual-best pairs (span-skip) -----------------
        {
            const unsigned a0 = aliveW[wave << 1], a1 = aliveW[(wave << 1) | 1];
            if (a0 | a1) {
                if (((lane < 32 ? a0 : a1) >> (lane & 31)) & 1u) {
                    const int c = rowHead[t];
                    if ((int)colHead[c] == t) {
                        out[N + t] = c;
                        atomicAnd(&aliveW[t >> 5], ~(1u << (t & 31)));
                        atomicOr(&usedW[c >> 5], 1u << (c & 31));
                        atomicAdd(&matched, 1);
                    }
                }
            }
        }
        __syncthreads();                                           // B1
        const int aliveCnt = N - matched;
        if (aliveCnt <= 0) break;

        // ---- phase 2a: repair row heads (span-skip) -----------------------
        {
            const unsigned a0 = aliveW[wave << 1], a1 = aliveW[(wave << 1) | 1];
            if (a0 | a1) {
                if (((lane < 32 ? a0 : a1) >> (lane & 31)) & 1u) {
                    int p = rowPtr[t]; int c = rowHead[t];
                    if ((usedW[c >> 5] >> (c & 31)) & 1u) {
                        if (p == SENT) { int q = atomicAdd(&rqn, 1); rowQ[q] = (unsigned short)t; }
                        else {
                            for (;;) {
                                ++p;
                                if (p >= K) { p = SENT; int q = atomicAdd(&rqn, 1); rowQ[q] = (unsigned short)t; break; }
                                c = rowList[t * K + p];
                                if (!((usedW[c >> 5] >> (c & 31)) & 1u)) { rowHead[t] = (unsigned short)c; break; }
                            }
                            rowPtr[t] = (unsigned char)p;
                        }
                    }
                }
            }
        }
        // ---- phase 2b: repair col heads (all-used span-skip) --------------
        {
            const unsigned u0 = usedW[wave << 1], u1 = usedW[(wave << 1) | 1];
            if ((u0 & u1) != 0xFFFFFFFFu) {
                if (!(((lane < 32 ? u0 : u1) >> (lane & 31)) & 1u)) {
                    int p = colPtr[t]; int r = colHead[t];
                    if (!((aliveW[r >> 5] >> (r & 31)) & 1u)) {
                        if (p == SENT) { int q = atomicAdd(&cqn, 1); colQ[q] = (unsigned short)t; }
                        else {
                            for (;;) {
                                ++p;
                                if (p >= K) { p = SENT; int q = atomicAdd(&cqn, 1); colQ[q] = (unsigned short)t; break; }
                                r = colList[t * K + p];
                                if ((aliveW[r >> 5] >> (r & 31)) & 1u) { colHead[t] = (unsigned short)r; break; }
                            }
                            colPtr[t] = (unsigned char)p;
                        }
                    }
                }
            }
        }
        __syncthreads();                                           // B2

        if (aliveCnt <= TAIL) { toTail = true; break; }            // queues pend -> tail

        // ---- phase 3: rescans (only when some list exhausted) -------------
        const int nr = rqn, nc = cqn;
        if (nr | nc) {
            const unsigned umU = (usedW[lane >> 1] >> ((lane & 1) << 4)) & 0xFFFFu;
            const unsigned umA = (aliveW[lane >> 1] >> ((lane & 1) << 4)) & 0xFFFFu;

            for (int i = wave; i < nr; i += 16) {
                const int r = rowQ[i];
                const float4* rp = (const float4*)(C + (size_t)r * N) + (lane << 2);
                float4 q0 = rp[0], q1 = rp[1], q2 = rp[2], q3 = rp[3];
                float v[16] = {q0.x, q0.y, q0.z, q0.w, q1.x, q1.y, q1.z, q1.w,
                               q2.x, q2.y, q2.z, q2.w, q3.x, q3.y, q3.z, q3.w};
                float bv = -INFINITY; int bc = N;
                #pragma unroll
                for (int k = 0; k < 16; ++k) {
                    float vv = ((umU >> k) & 1u) ? -INFINITY : v[k];
                    if (vv > bv) { bv = vv; bc = (lane << 4) + k; }
                }
                wave_argmax(bv, bc);
                if (lane == 0) rowHead[r] = (unsigned short)bc;
            }
            if (haveCT) {
                for (int i = wave; i < nc; i += 16) {
                    const int c = colQ[i];
                    const float4* cp = (const float4*)(CT + (size_t)c * N) + (lane << 2);
                    float4 q0 = cp[0], q1 = cp[1], q2 = cp[2], q3 = cp[3];
                    float v[16] = {q0.x, q0.y, q0.z, q0.w, q1.x, q1.y, q1.z, q1.w,
                                   q2.x, q2.y, q2.z, q2.w, q3.x, q3.y, q3.z, q3.w};
                    float bv = -INFINITY; int br = N;
                    #pragma unroll
                    for (int k = 0; k < 16; ++k) {
                        float vv = ((umA >> k) & 1u) ? v[k] : -INFINITY;
                        if (vv > bv) { bv = vv; br = (lane << 4) + k; }
                    }
                    wave_argmax(bv, br);
                    if (lane == 0) colHead[c] = (unsigned short)br;
                }
            } else {
                for (int i = wave; i < nc; i += 16) {
                    const int c = colQ[i];
                    float bv = -INFINITY; int br = N;
                    #pragma unroll
                    for (int k = 0; k < 16; ++k) {
                        const int r = (k << 6) + lane;
                        bool a = (aliveW[(k << 1) + (lane >> 5)] >> (lane & 31)) & 1u;
                        float vv = a ? C[(size_t)r * N + c] : -INFINITY;
                        if (vv > bv) { bv = vv; br = r; }
                    }
                    wave_argmax(bv, br);
                    if (lane == 0) colHead[c] = (unsigned short)br;
                }
            }
            __syncthreads();                                       // B3
        }
    }

    if (!toTail) { out[t] = t; return; }
    if (wave != 0) { out[t] = t; return; }        // waves 1..15 done (no more barriers)

    // ================= wave-0 tail (barrier-free rounds) ====================
    for (int it = 0; it < 3000; ++it) {
        // --- A: process pending rescan queues ------------------------------
        {
            const int nr = rqn, nc = cqn;
            if (nr | nc) {
                const unsigned umU = (usedW[lane >> 1] >> ((lane & 1) << 4)) & 0xFFFFu;
                const unsigned umA = (aliveW[lane >> 1] >> ((lane & 1) << 4)) & 0xFFFFu;
                for (int i = 0; i < nr; ++i) {
                    const int r = rowQ[i];
                    const float4* rp = (const float4*)(C + (size_t)r * N) + (lane << 2);
                    float4 q0 = rp[0], q1 = rp[1], q2 = rp[2], q3 = rp[3];
                    float v[16] = {q0.x, q0.y, q0.z, q0.w, q1.x, q1.y, q1.z, q1.w,
                                   q2.x, q2.y, q2.z, q2.w, q3.x, q3.y, q3.z, q3.w};
                    float bv = -INFINITY; int bc = N;
                    #pragma unroll
                    for (int k = 0; k < 16; ++k) {
                        float vv = ((umU >> k) & 1u) ? -INFINITY : v[k];
                        if (vv > bv) { bv = vv; bc = (lane << 4) + k; }
                    }
                    wave_argmax(bv, bc);
                    if (lane == 0) rowHead[r] = (unsigned short)bc;
                }
                if (haveCT) {
                    for (int i = 0; i < nc; ++i) {
                        const int c = colQ[i];
                        const float4* cp = (const float4*)(CT + (size_t)c * N) + (lane << 2);
                        float4 q0 = cp[0], q1 = cp[1], q2 = cp[2], q3 = cp[3];
                        float v[16] = {q0.x, q0.y, q0.z, q0.w, q1.x, q1.y, q1.z, q1.w,
                                       q2.x, q2.y, q2.z, q2.w, q3.x, q3.y, q3.z, q3.w};
                        float bv = -INFINITY; int br = N;
                        #pragma unroll
                        for (int k = 0; k < 16; ++k) {
                            float vv = ((umA >> k) & 1u) ? v[k] : -INFINITY;
                            if (vv > bv) { bv = vv; br = (lane << 4) + k; }
                        }
                        wave_argmax(bv, br);
                        if (lane == 0) colHead[c] = (unsigned short)br;
                    }
                } else {
                    for (int i = 0; i < nc; ++i) {
                        const int c = colQ[i];
                        float bv = -INFINITY; int br = N;
                        #pragma unroll
                        for (int k = 0; k < 16; ++k) {
                            const int r = (k << 6) + lane;
                            bool a = (aliveW[(k << 1) + (lane >> 5)] >> (lane & 31)) & 1u;
                            float vv = a ? C[(size_t)r * N + c] : -INFINITY;
                            if (vv > bv) { bv = vv; br = r; }
                        }
                        wave_argmax(bv, br);
                        if (lane == 0) colHead[c] = (unsigned short)br;
                    }
                }
            }
        }
        WF();
        // --- B: match mutual pairs (span-skip sweeps) ----------------------
        for (int sp = 0; sp < 16; ++sp) {
            const unsigned a0 = aliveW[sp << 1], a1 = aliveW[(sp << 1) | 1];
            if ((a0 | a1) == 0u) continue;
            const int r = (sp << 6) + lane;
            if (((lane < 32 ? a0 : a1) >> (lane & 31)) & 1u) {
                const int c = rowHead[r];
                if ((int)colHead[c] == r) {
                    out[N + r] = c;
                    atomicAnd(&aliveW[r >> 5], ~(1u << (r & 31)));
                    atomicOr(&usedW[c >> 5], 1u << (c & 31));
                    atomicAdd(&matched, 1);
                }
            }
        }
        WF();
        // --- C: done? reset queues -----------------------------------------
        if (matched >= N) break;
        if (lane == 0) { rqn = 0; cqn = 0; }
        WF();
        // --- E: repairs (span-skip) ----------------------------------------
        for (int sp = 0; sp < 16; ++sp) {
            const unsigned a0 = aliveW[sp << 1], a1 = aliveW[(sp << 1) | 1];
            if ((a0 | a1) == 0u) continue;
            const int r = (sp << 6) + lane;
            if (((lane < 32 ? a0 : a1) >> (lane & 31)) & 1u) {
                int p = rowPtr[r]; int c = rowHead[r];
                if ((usedW[c >> 5] >> (c & 31)) & 1u) {
                    if (p == SENT) { int q = atomicAdd(&rqn, 1); rowQ[q] = (unsigned short)r; }
                    else {
                        for (;;) {
                            ++p;
                            if (p >= K) { p = SENT; int q = atomicAdd(&rqn, 1); rowQ[q] = (unsigned short)r; break; }
                            c = rowList[r * K + p];
                            if (!((usedW[c >> 5] >> (c & 31)) & 1u)) { rowHead[r] = (unsigned short)c; break; }
                        }
                        rowPtr[r] = (unsigned char)p;
                    }
                }
            }
        }
        for (int sp = 0; sp < 16; ++sp) {
            const unsigned u0 = usedW[sp << 1], u1 = usedW[(sp << 1) | 1];
            if ((u0 & u1) == 0xFFFFFFFFu) continue;
            const int c0 = (sp << 6) + lane;
            if (!(((lane < 32 ? u0 : u1) >> (lane & 31)) & 1u)) {
                int p = colPtr[c0]; int r = colHead[c0];
                if (!((aliveW[r >> 5] >> (r & 31)) & 1u)) {
                    if (p == SENT) { int q = atomicAdd(&cqn, 1); colQ[q] = (unsigned short)c0; }
                    else {
                        for (;;) {
                            ++p;
                            if (p >= K) { p = SENT; int q = atomicAdd(&cqn, 1); colQ[q] = (unsigned short)c0; break; }
                            r = colList[c0 * K + p];
                            if ((aliveW[r >> 5] >> (r & 31)) & 1u) { colHead[c0] = (unsigned short)r; break; }
                        }
                        colPtr[c0] = (unsigned char)p;
                    }
                }
            }
        }
        WF();
    }
    out[lane] = lane;    // wave 0's identity slice
}

// ---------------------------------------------------------------------------
// Fallback (tiny ws): self-contained rounds kernel (alive-list full rescan).
// ---------------------------------------------------------------------------
__device__ __forceinline__ unsigned ordf(unsigned u) {
    return u ^ (unsigned)(((int)u >> 31) | (int)0x80000000);
}
__global__ __launch_bounds__(1024) void rounds_fallback(const float* __restrict__ C,
                                                        int* __restrict__ out) {
    __shared__ unsigned long long ck[N];
    __shared__ unsigned rbc[N];
    __shared__ unsigned short aliveList[2][N];
    __shared__ unsigned colUsedW[N / 32];
    __shared__ int cnts[2];
    const int tid = threadIdx.x;
    const int lane = tid & 63;
    const int wave = tid >> 6;
    aliveList[0][tid] = (unsigned short)tid;
    if (tid < N / 32) colUsedW[tid] = 0u;
    if (tid == 0) { cnts[0] = N; cnts[1] = 0; }
    __syncthreads();
    int p = 0;
    for (int round = 0; round < N + 2; ++round) {
        const int cnt = cnts[p];
        ck[tid] = 0ULL;
        if (tid == 0) cnts[p ^ 1] = 0;
        __syncthreads();
        const unsigned um = (colUsedW[lane >> 1] >> ((lane & 1) << 4)) & 0xFFFFu;
        unsigned cHi[16]; unsigned cRow[16];
        #pragma unroll
        for (int k = 0; k < 16; ++k) { cHi[k] = 0u; cRow[k] = 0u; }
        bool any = false;
        for (int i = wave; i < cnt; i += 16) {
            const int r = aliveList[p][i];
            any = true;
            const float4* rp = (const float4*)(C + (size_t)r * N) + (lane << 2);
            float4 q0 = rp[0], q1 = rp[1], q2 = rp[2], q3 = rp[3];
            float v[16] = {q0.x, q0.y, q0.z, q0.w, q1.x, q1.y, q1.z, q1.w,
                           q2.x, q2.y, q2.z, q2.w, q3.x, q3.y, q3.z, q3.w};
            float bv = -INFINITY; int bc = 0;
            #pragma unroll
            for (int k = 0; k < 16; ++k) {
                unsigned ou = ordf(__float_as_uint(v[k]));
                if (ou > cHi[k] || (ou == cHi[k] && (unsigned)r < cRow[k])) {
                    cHi[k] = ou; cRow[k] = (unsigned)r;
                }
                float vv = ((um >> k) & 1u) ? -INFINITY : v[k];
                if (vv > bv) { bv = vv; bc = (lane << 4) + k; }
            }
            wave_argmax(bv, bc);
            if (lane == 0) rbc[r] = (unsigned)bc;
        }
        if (any) {
            #pragma unroll
            for (int k = 0; k < 16; ++k)
                atomicMax(&ck[(k << 6) | lane],
                          ((unsigned long long)cHi[k] << 32) |
                          (unsigned long long)(N - 1 - cRow[k]));
        }
        __syncthreads();
        if (tid < cnt) {
            const int r = aliveList[p][tid];
            const int c = (int)rbc[r];
            const unsigned long long k64 = ck[((c & 15) << 6) | (c >> 4)];
            const int winner = (N - 1) - (int)(unsigned)(k64 & 0xFFFFFFFFull);
            if (winner == r) {
                out[N + r] = c;
                atomicOr(&colUsedW[c >> 5], 1u << (c & 31));
            } else {
                int idx = atomicAdd(&cnts[p ^ 1], 1);
                aliveList[p ^ 1][idx] = (unsigned short)r;
            }
        }
        __syncthreads();
        p ^= 1;
        if (cnts[p] == 0) break;
    }
    out[tid] = tid;
}

// ---------------------------------------------------------------------------
extern "C" void kernel_launch(void* const* d_in, const int* in_sizes, int n_in,
                              void* d_out, int out_size, void* d_ws, size_t ws_size,
                              hipStream_t stream) {
    const float* C = (const float*)d_in[0];
    int* out = (int*)d_out;

    const size_t listBytes = (size_t)2 * N * K * sizeof(unsigned short);  // 64 KB
    const size_t ctBytes   = (size_t)N * N * sizeof(float);               // 4 MB

    if (ws_size >= listBytes + ctBytes) {
        unsigned short* rowListG = (unsigned short*)d_ws;
        unsigned short* colListG = rowListG + N * K;
        float* CT = (float*)((char*)d_ws + listBytes);
        init_fused<<<512, 256, 0, stream>>>(C, CT, rowListG);     // transpose || row topK
        topk_kernel<<<256, 256, 0, stream>>>(CT, colListG);       // col topK
        rounds_fast<<<1, 1024, 0, stream>>>(C, CT, rowListG, colListG, out, 1);
    } else if (ws_size >= listBytes) {
        unsigned short* rowListG = (unsigned short*)d_ws;
        unsigned short* colListG = rowListG + N * K;
        topk_kernel<<<256, 256, 0, stream>>>(C, rowListG);
        topk_cols<<<64, 1024, 0, stream>>>(C, colListG);
        rounds_fast<<<1, 1024, 0, stream>>>(C, C, rowListG, colListG, out, 0);
    } else {
        rounds_fallback<<<1, 1024, 0, stream>>>(C, out);
    }
}

// Round 13
// 87.125 us; speedup vs baseline: 3.0227x; 3.0227x over previous
//
#include <hip/hip_runtime.h>
#include <math.h>

#define N 1024
#define K 16
#define SENT 255

// (v2,f2) beats (v1,f1): larger value wins; tie -> smaller index
__device__ __forceinline__ bool better(float v2, int f2, float v1, int f1) {
    return (v2 > v1) || (v2 == v1 && f2 < f1);
}

template<int CTRL>
__device__ __forceinline__ void dpp_step(float& v, int& f) {
    int ovi = __builtin_amdgcn_update_dpp(0, __float_as_int(v), CTRL, 0xF, 0xF, true);
    int ofi = __builtin_amdgcn_update_dpp(0, f, CTRL, 0xF, 0xF, true);
    float ov = __int_as_float(ovi);
    if (better(ov, ofi, v, f)) { v = ov; f = ofi; }
}

// Full-wave argmax on (v,f); result broadcast to all lanes.
__device__ __forceinline__ void wave_argmax(float& v, int& f) {
    dpp_step<0xB1>(v, f);
    dpp_step<0x4E>(v, f);
    dpp_step<0x141>(v, f);
    dpp_step<0x140>(v, f);
    float v0 = __int_as_float(__builtin_amdgcn_readlane(__float_as_int(v), 0));
    int   f0 = __builtin_amdgcn_readlane(f, 0);
    float v1 = __int_as_float(__builtin_amdgcn_readlane(__float_as_int(v), 16));
    int   f1 = __builtin_amdgcn_readlane(f, 16);
    float v2 = __int_as_float(__builtin_amdgcn_readlane(__float_as_int(v), 32));
    int   f2 = __builtin_amdgcn_readlane(f, 32);
    float v3 = __int_as_float(__builtin_amdgcn_readlane(__float_as_int(v), 48));
    int   f3 = __builtin_amdgcn_readlane(f, 48);
    if (better(v1, f1, v0, f0)) { v0 = v1; f0 = f1; }
    if (better(v3, f3, v2, f2)) { v2 = v3; f2 = f3; }
    if (better(v2, f2, v0, f0)) { v0 = v2; f0 = f2; }
    v = v0; f = f0;
}

// top-K of one row of M (val desc, idx asc), one wave, coalesced.
__device__ __forceinline__ void topk_row_body(const float* __restrict__ M,
                                              unsigned short* __restrict__ listG,
                                              int row, int lane) {
    const float* rp = M + (size_t)row * N;
    float rv[16];
    #pragma unroll
    for (int k = 0; k < 16; ++k) rv[k] = rp[(k << 6) + lane];
    unsigned excl = 0;
    for (int pass = 0; pass < K; ++pass) {
        float best = -INFINITY; int bc = N;
        #pragma unroll
        for (int k = 0; k < 16; ++k) {
            int c = (k << 6) + lane;
            if (!((excl >> k) & 1u) && rv[k] > best) { best = rv[k]; bc = c; }
        }
        wave_argmax(best, bc);
        if (lane == (bc & 63)) excl |= 1u << (bc >> 6);
        if (lane == 0) listG[row * K + pass] = (unsigned short)bc;
    }
}

// ---------------------------------------------------------------------------
// K1: blocks 0..255 transpose 64x64 tiles C->CT; blocks 256..511 do row topK.
// ---------------------------------------------------------------------------
__global__ __launch_bounds__(256) void init_fused(const float* __restrict__ C,
                                                  float* __restrict__ CT,
                                                  unsigned short* __restrict__ rowListG) {
    const int b = blockIdx.x;
    if (b < 256) {
        __shared__ float T[64][65];
        const int t = threadIdx.x;
        const int tx = t & 63, ty = t >> 6;
        const int bi = b >> 4, bj = b & 15;
        #pragma unroll
        for (int k = 0; k < 16; ++k) {
            int r = (bi << 6) + ty + (k << 2);
            T[ty + (k << 2)][tx] = C[(size_t)r * N + (bj << 6) + tx];
        }
        __syncthreads();
        #pragma unroll
        for (int k = 0; k < 16; ++k) {
            int c = (bj << 6) + ty + (k << 2);
            CT[(size_t)c * N + (bi << 6) + tx] = T[tx][ty + (k << 2)];
        }
    } else {
        const int row = ((b - 256) << 2) + (threadIdx.x >> 6);
        topk_row_body(C, rowListG, row, threadIdx.x & 63);
    }
}

// ---------------------------------------------------------------------------
// K2: col topK = row topK of CT.
// ---------------------------------------------------------------------------
__global__ __launch_bounds__(256) void topk_kernel(const float* __restrict__ M,
                                                   unsigned short* __restrict__ listG) {
    int row  = (blockIdx.x * blockDim.x + threadIdx.x) >> 6;
    int lane = threadIdx.x & 63;
    if (row >= N) return;
    topk_row_body(M, listG, row, lane);
}

// ---------------------------------------------------------------------------
// Legacy col top-K via LDS tiles (mid-ws path only).
// ---------------------------------------------------------------------------
__global__ __launch_bounds__(1024) void topk_cols(const float* __restrict__ C,
                                                  unsigned short* __restrict__ colListG) {
    __shared__ float T[16][1025];
    const int t  = threadIdx.x;
    const int c0 = blockIdx.x << 4;
    const int cc = t & 15;
    const int tr = t >> 4;
    #pragma unroll
    for (int k = 0; k < 16; ++k) {
        int r = (k << 6) + tr;
        T[cc][r] = C[(size_t)r * N + c0 + cc];
    }
    __syncthreads();
    const int wave = t >> 6;
    const int lane = t & 63;
    const int c = c0 + wave;
    float rv[16];
    #pragma unroll
    for (int k = 0; k < 16; ++k) rv[k] = T[wave][(k << 6) + lane];
    unsigned excl = 0;
    for (int pass = 0; pass < K; ++pass) {
        float best = -INFINITY; int br = N;
        #pragma unroll
        for (int k = 0; k < 16; ++k) {
            int r = (k << 6) + lane;
            if (!((excl >> k) & 1u) && rv[k] > best) { best = rv[k]; br = r; }
        }
        wave_argmax(best, br);
        if (lane == (br & 63)) excl |= 1u << (br >> 6);
        if (lane == 0) colListG[c * K + pass] = (unsigned short)br;
    }
}

// ---------------------------------------------------------------------------
// K3 rounds: R10 structure (16 waves, 2-3 barriers/round) + span-skip.
// ---------------------------------------------------------------------------
__global__ __launch_bounds__(1024) void rounds_fast(const float* __restrict__ C,
                                                    const float* __restrict__ CT,
                                                    const unsigned short* __restrict__ rowListG,
                                                    const unsigned short* __restrict__ colListG,
                                                    int* __restrict__ out,
                                                    int haveCT) {
    __shared__ unsigned short rowList[N * K];   // 32 KB
    __shared__ unsigned short colList[N * K];   // 32 KB
    __shared__ unsigned short rowHead[N];
    __shared__ unsigned short colHead[N];
    __shared__ unsigned char  rowPtr[N], colPtr[N];
    __shared__ unsigned aliveW[N / 32], usedW[N / 32];
    __shared__ unsigned short rowQ[N], colQ[N];
    __shared__ int rqn, cqn, matched;

    const int t = threadIdx.x;
    const int lane = t & 63;
    const int wave = t >> 6;

    #pragma unroll
    for (int i = 0; i < 2; ++i) {
        ((uint4*)rowList)[i * 1024 + t] = ((const uint4*)rowListG)[i * 1024 + t];
        ((uint4*)colList)[i * 1024 + t] = ((const uint4*)colListG)[i * 1024 + t];
    }
    rowPtr[t] = 0; colPtr[t] = 0;
    if (t < N / 32) { aliveW[t] = 0xFFFFFFFFu; usedW[t] = 0u; }
    if (t == 0) { matched = 0; rqn = 0; cqn = 0; }
    __syncthreads();
    rowHead[t] = rowList[t * K];
    colHead[t] = colList[t * K];
    __syncthreads();

    for (int round = 0; round < N + 8; ++round) {
        if (t == 0) { rqn = 0; cqn = 0; }
        // ---- phase 1: match mutual-best pairs (span-skip) -----------------
        {
            const unsigned a0 = aliveW[wave << 1], a1 = aliveW[(wave << 1) | 1];
            if (a0 | a1) {
                if (((lane < 32 ? a0 : a1) >> (lane & 31)) & 1u) {
                    const int c = rowHead[t];
                    if ((int)colHead[c] == t) {
                        out[N + t] = c;
                        atomicAnd(&aliveW[t >> 5], ~(1u << (t & 31)));
                        atomicOr(&usedW[c >> 5], 1u << (c & 31));
                        atomicAdd(&matched, 1);
                    }
                }
            }
        }
        __syncthreads();                                           // B1
        if (matched >= N) break;

        // ---- phase 2a: repair row heads (span-skip) -----------------------
        {
            const unsigned a0 = aliveW[wave << 1], a1 = aliveW[(wave << 1) | 1];
            if (a0 | a1) {
                if (((lane < 32 ? a0 : a1) >> (lane & 31)) & 1u) {
                    int p = rowPtr[t]; int c = rowHead[t];
                    if ((usedW[c >> 5] >> (c & 31)) & 1u) {
                        if (p == SENT) { int q = atomicAdd(&rqn, 1); rowQ[q] = (unsigned short)t; }
                        else {
                            for (;;) {
                                ++p;
                                if (p >= K) { p = SENT; int q = atomicAdd(&rqn, 1); rowQ[q] = (unsigned short)t; break; }
                                c = rowList[t * K + p];
                                if (!((usedW[c >> 5] >> (c & 31)) & 1u)) { rowHead[t] = (unsigned short)c; break; }
                            }
                            rowPtr[t] = (unsigned char)p;
                        }
                    }
                }
            }
        }
        // ---- phase 2b: repair col heads (all-used span-skip) --------------
        {
            const unsigned u0 = usedW[wave << 1], u1 = usedW[(wave << 1) | 1];
            if ((u0 & u1) != 0xFFFFFFFFu) {
                if (!(((lane < 32 ? u0 : u1) >> (lane & 31)) & 1u)) {
                    int p = colPtr[t]; int r = colHead[t];
                    if (!((aliveW[r >> 5] >> (r & 31)) & 1u)) {
                        if (p == SENT) { int q = atomicAdd(&cqn, 1); colQ[q] = (unsigned short)t; }
                        else {
                            for (;;) {
                                ++p;
                                if (p >= K) { p = SENT; int q = atomicAdd(&cqn, 1); colQ[q] = (unsigned short)t; break; }
                                r = colList[t * K + p];
                                if ((aliveW[r >> 5] >> (r & 31)) & 1u) { colHead[t] = (unsigned short)r; break; }
                            }
                            colPtr[t] = (unsigned char)p;
                        }
                    }
                }
            }
        }
        __syncthreads();                                           // B2

        // ---- phase 3: rescans (only when some list exhausted) -------------
        const int nr = rqn, nc = cqn;
        if (nr | nc) {
            const unsigned umU = (usedW[lane >> 1] >> ((lane & 1) << 4)) & 0xFFFFu;
            const unsigned umA = (aliveW[lane >> 1] >> ((lane & 1) << 4)) & 0xFFFFu;

            for (int i = wave; i < nr; i += 16) {
                const int r = rowQ[i];
                const float4* rp = (const float4*)(C + (size_t)r * N) + (lane << 2);
                float4 q0 = rp[0], q1 = rp[1], q2 = rp[2], q3 = rp[3];
                float v[16] = {q0.x, q0.y, q0.z, q0.w, q1.x, q1.y, q1.z, q1.w,
                               q2.x, q2.y, q2.z, q2.w, q3.x, q3.y, q3.z, q3.w};
                float bv = -INFINITY; int bc = N;
                #pragma unroll
                for (int k = 0; k < 16; ++k) {
                    float vv = ((umU >> k) & 1u) ? -INFINITY : v[k];
                    if (vv > bv) { bv = vv; bc = (lane << 4) + k; }
                }
                wave_argmax(bv, bc);
                if (lane == 0) rowHead[r] = (unsigned short)bc;
            }
            if (haveCT) {
                for (int i = wave; i < nc; i += 16) {
                    const int c = colQ[i];
                    const float4* cp = (const float4*)(CT + (size_t)c * N) + (lane << 2);
                    float4 q0 = cp[0], q1 = cp[1], q2 = cp[2], q3 = cp[3];
                    float v[16] = {q0.x, q0.y, q0.z, q0.w, q1.x, q1.y, q1.z, q1.w,
                                   q2.x, q2.y, q2.z, q2.w, q3.x, q3.y, q3.z, q3.w};
                    float bv = -INFINITY; int br = N;
                    #pragma unroll
                    for (int k = 0; k < 16; ++k) {
                        float vv = ((umA >> k) & 1u) ? v[k] : -INFINITY;
                        if (vv > bv) { bv = vv; br = (lane << 4) + k; }
                    }
                    wave_argmax(bv, br);
                    if (lane == 0) colHead[c] = (unsigned short)br;
                }
            } else {
                for (int i = wave; i < nc; i += 16) {
                    const int c = colQ[i];
                    float bv = -INFINITY; int br = N;
                    #pragma unroll
                    for (int k = 0; k < 16; ++k) {
                        const int r = (k << 6) + lane;
                        bool a = (aliveW[(k << 1) + (lane >> 5)] >> (lane & 31)) & 1u;
                        float vv = a ? C[(size_t)r * N + c] : -INFINITY;
                        if (vv > bv) { bv = vv; br = r; }
                    }
                    wave_argmax(bv, br);
                    if (lane == 0) colHead[c] = (unsigned short)br;
                }
            }
            __syncthreads();                                       // B3
        }
    }

    out[t] = t;   // row-index half: identity
}

// ---------------------------------------------------------------------------
// Fallback (tiny ws): self-contained rounds kernel (alive-list full rescan).
// ---------------------------------------------------------------------------
__device__ __forceinline__ unsigned ordf(unsigned u) {
    return u ^ (unsigned)(((int)u >> 31) | (int)0x80000000);
}
__global__ __launch_bounds__(1024) void rounds_fallback(const float* __restrict__ C,
                                                        int* __restrict__ out) {
    __shared__ unsigned long long ck[N];
    __shared__ unsigned rbc[N];
    __shared__ unsigned short aliveList[2][N];
    __shared__ unsigned colUsedW[N / 32];
    __shared__ int cnts[2];
    const int tid = threadIdx.x;
    const int lane = tid & 63;
    const int wave = tid >> 6;
    aliveList[0][tid] = (unsigned short)tid;
    if (tid < N / 32) colUsedW[tid] = 0u;
    if (tid == 0) { cnts[0] = N; cnts[1] = 0; }
    __syncthreads();
    int p = 0;
    for (int round = 0; round < N + 2; ++round) {
        const int cnt = cnts[p];
        ck[tid] = 0ULL;
        if (tid == 0) cnts[p ^ 1] = 0;
        __syncthreads();
        const unsigned um = (colUsedW[lane >> 1] >> ((lane & 1) << 4)) & 0xFFFFu;
        unsigned cHi[16]; unsigned cRow[16];
        #pragma unroll
        for (int k = 0; k < 16; ++k) { cHi[k] = 0u; cRow[k] = 0u; }
        bool any = false;
        for (int i = wave; i < cnt; i += 16) {
            const int r = aliveList[p][i];
            any = true;
            const float4* rp = (const float4*)(C + (size_t)r * N) + (lane << 2);
            float4 q0 = rp[0], q1 = rp[1], q2 = rp[2], q3 = rp[3];
            float v[16] = {q0.x, q0.y, q0.z, q0.w, q1.x, q1.y, q1.z, q1.w,
                           q2.x, q2.y, q2.z, q2.w, q3.x, q3.y, q3.z, q3.w};
            float bv = -INFINITY; int bc = 0;
            #pragma unroll
            for (int k = 0; k < 16; ++k) {
                unsigned ou = ordf(__float_as_uint(v[k]));
                if (ou > cHi[k] || (ou == cHi[k] && (unsigned)r < cRow[k])) {
                    cHi[k] = ou; cRow[k] = (unsigned)r;
                }
                float vv = ((um >> k) & 1u) ? -INFINITY : v[k];
                if (vv > bv) { bv = vv; bc = (lane << 4) + k; }
            }
            wave_argmax(bv, bc);
            if (lane == 0) rbc[r] = (unsigned)bc;
        }
        if (any) {
            #pragma unroll
            for (int k = 0; k < 16; ++k)
                atomicMax(&ck[(k << 6) | lane],
                          ((unsigned long long)cHi[k] << 32) |
                          (unsigned long long)(N - 1 - cRow[k]));
        }
        __syncthreads();
        if (tid < cnt) {
            const int r = aliveList[p][tid];
            const int c = (int)rbc[r];
            const unsigned long long k64 = ck[((c & 15) << 6) | (c >> 4)];
            const int winner = (N - 1) - (int)(unsigned)(k64 & 0xFFFFFFFFull);
            if (winner == r) {
                out[N + r] = c;
                atomicOr(&colUsedW[c >> 5], 1u << (c & 31));
            } else {
                int idx = atomicAdd(&cnts[p ^ 1], 1);
                aliveList[p ^ 1][idx] = (unsigned short)r;
            }
        }
        __syncthreads();
        p ^= 1;
        if (cnts[p] == 0) break;
    }
    out[tid] = tid;
}

// ---------------------------------------------------------------------------
extern "C" void kernel_launch(void* const* d_in, const int* in_sizes, int n_in,
                              void* d_out, int out_size, void* d_ws, size_t ws_size,
                              hipStream_t stream) {
    const float* C = (const float*)d_in[0];
    int* out = (int*)d_out;

    const size_t listBytes = (size_t)2 * N * K * sizeof(unsigned short);  // 64 KB
    const size_t ctBytes   = (size_t)N * N * sizeof(float);               // 4 MB

    if (ws_size >= listBytes + ctBytes) {
        unsigned short* rowListG = (unsigned short*)d_ws;
        unsigned short* colListG = rowListG + N * K;
        float* CT = (float*)((char*)d_ws + listBytes);
        init_fused<<<512, 256, 0, stream>>>(C, CT, rowListG);     // transpose || row topK
        topk_kernel<<<256, 256, 0, stream>>>(CT, colListG);       // col topK
        rounds_fast<<<1, 1024, 0, stream>>>(C, CT, rowListG, colListG, out, 1);
    } else if (ws_size >= listBytes) {
        unsigned short* rowListG = (unsigned short*)d_ws;
        unsigned short* colListG = rowListG + N * K;
        topk_kernel<<<256, 256, 0, stream>>>(C, rowListG);
        topk_cols<<<64, 1024, 0, stream>>>(C, colListG);
        rounds_fast<<<1, 1024, 0, stream>>>(C, C, rowListG, colListG, out, 0);
    } else {
        rounds_fallback<<<1, 1024, 0, stream>>>(C, out);
    }
}

// Round 14
// 78.597 us; speedup vs baseline: 3.3507x; 1.1085x over previous
//
#include <hip/hip_runtime.h>
#include <math.h>

#define N 1024
#define K 16
#define SENT 255

// (v2,f2) beats (v1,f1): larger value wins; tie -> smaller index
__device__ __forceinline__ bool better(float v2, int f2, float v1, int f1) {
    return (v2 > v1) || (v2 == v1 && f2 < f1);
}

template<int CTRL>
__device__ __forceinline__ void dpp_step(float& v, int& f) {
    int ovi = __builtin_amdgcn_update_dpp(0, __float_as_int(v), CTRL, 0xF, 0xF, true);
    int ofi = __builtin_amdgcn_update_dpp(0, f, CTRL, 0xF, 0xF, true);
    float ov = __int_as_float(ovi);
    if (better(ov, ofi, v, f)) { v = ov; f = ofi; }
}

// Full-wave argmax on (v,f); result broadcast to all lanes.
__device__ __forceinline__ void wave_argmax(float& v, int& f) {
    dpp_step<0xB1>(v, f);
    dpp_step<0x4E>(v, f);
    dpp_step<0x141>(v, f);
    dpp_step<0x140>(v, f);
    float v0 = __int_as_float(__builtin_amdgcn_readlane(__float_as_int(v), 0));
    int   f0 = __builtin_amdgcn_readlane(f, 0);
    float v1 = __int_as_float(__builtin_amdgcn_readlane(__float_as_int(v), 16));
    int   f1 = __builtin_amdgcn_readlane(f, 16);
    float v2 = __int_as_float(__builtin_amdgcn_readlane(__float_as_int(v), 32));
    int   f2 = __builtin_amdgcn_readlane(f, 32);
    float v3 = __int_as_float(__builtin_amdgcn_readlane(__float_as_int(v), 48));
    int   f3 = __builtin_amdgcn_readlane(f, 48);
    if (better(v1, f1, v0, f0)) { v0 = v1; f0 = f1; }
    if (better(v3, f3, v2, f2)) { v2 = v3; f2 = f3; }
    if (better(v2, f2, v0, f0)) { v0 = v2; f0 = f2; }
    v = v0; f = f0;
}

// top-K of one row of M (val desc, idx asc), one wave, coalesced.
__device__ __forceinline__ void topk_row_body(const float* __restrict__ M,
                                              unsigned short* __restrict__ listG,
                                              int row, int lane) {
    const float* rp = M + (size_t)row * N;
    float rv[16];
    #pragma unroll
    for (int k = 0; k < 16; ++k) rv[k] = rp[(k << 6) + lane];
    unsigned excl = 0;
    for (int pass = 0; pass < K; ++pass) {
        float best = -INFINITY; int bc = N;
        #pragma unroll
        for (int k = 0; k < 16; ++k) {
            int c = (k << 6) + lane;
            if (!((excl >> k) & 1u) && rv[k] > best) { best = rv[k]; bc = c; }
        }
        wave_argmax(best, bc);
        if (lane == (bc & 63)) excl |= 1u << (bc >> 6);
        if (lane == 0) listG[row * K + pass] = (unsigned short)bc;
    }
}

// ---------------------------------------------------------------------------
// K1: vectorized tiled transpose C -> CT (64x64 tiles, float4 both sides).
// ---------------------------------------------------------------------------
__global__ __launch_bounds__(256) void transpose_k(const float* __restrict__ C,
                                                   float* __restrict__ CT) {
    __shared__ float T[64][65];
    const int t = threadIdx.x;
    const int bi = blockIdx.x, bj = blockIdx.y;
    const int jr = (t & 15) << 2;   // 0..60 step 4
    const int g  = t >> 4;          // 0..15
    #pragma unroll
    for (int k = 0; k < 4; ++k) {
        const int r = g + (k << 4);
        float4 v = *(const float4*)(C + (size_t)((bi << 6) + r) * N + (bj << 6) + jr);
        T[r][jr] = v.x; T[r][jr + 1] = v.y; T[r][jr + 2] = v.z; T[r][jr + 3] = v.w;
    }
    __syncthreads();
    #pragma unroll
    for (int k = 0; k < 4; ++k) {
        const int c = g + (k << 4);
        float4 w = make_float4(T[jr][c], T[jr + 1][c], T[jr + 2][c], T[jr + 3][c]);
        *(float4*)(CT + (size_t)((bj << 6) + c) * N + (bi << 6) + jr) = w;
    }
}

// ---------------------------------------------------------------------------
// K2: merged top-K: waves 0..1023 scan C rows -> rowList; 1024..2047 scan CT.
// ---------------------------------------------------------------------------
__global__ __launch_bounds__(256) void topk_both(const float* __restrict__ C,
                                                 const float* __restrict__ CT,
                                                 unsigned short* __restrict__ rowListG,
                                                 unsigned short* __restrict__ colListG) {
    int gw   = (blockIdx.x * blockDim.x + threadIdx.x) >> 6;
    int lane = threadIdx.x & 63;
    if (gw < N) topk_row_body(C, rowListG, gw, lane);
    else        topk_row_body(CT, colListG, gw - N, lane);
}

// ---------------------------------------------------------------------------
// Standalone row top-K + legacy col top-K (fallback paths only).
// ---------------------------------------------------------------------------
__global__ __launch_bounds__(256) void topk_kernel(const float* __restrict__ M,
                                                   unsigned short* __restrict__ listG) {
    int row  = (blockIdx.x * blockDim.x + threadIdx.x) >> 6;
    int lane = threadIdx.x & 63;
    if (row >= N) return;
    topk_row_body(M, listG, row, lane);
}

__global__ __launch_bounds__(1024) void topk_cols(const float* __restrict__ C,
                                                  unsigned short* __restrict__ colListG) {
    __shared__ float T[16][1025];
    const int t  = threadIdx.x;
    const int c0 = blockIdx.x << 4;
    const int cc = t & 15;
    const int tr = t >> 4;
    #pragma unroll
    for (int k = 0; k < 16; ++k) {
        int r = (k << 6) + tr;
        T[cc][r] = C[(size_t)r * N + c0 + cc];
    }
    __syncthreads();
    const int wave = t >> 6;
    const int lane = t & 63;
    const int c = c0 + wave;
    float rv[16];
    #pragma unroll
    for (int k = 0; k < 16; ++k) rv[k] = T[wave][(k << 6) + lane];
    unsigned excl = 0;
    for (int pass = 0; pass < K; ++pass) {
        float best = -INFINITY; int br = N;
        #pragma unroll
        for (int k = 0; k < 16; ++k) {
            int r = (k << 6) + lane;
            if (!((excl >> k) & 1u) && rv[k] > best) { best = rv[k]; br = r; }
        }
        wave_argmax(best, br);
        if (lane == (br & 63)) excl |= 1u << (br >> 6);
        if (lane == 0) colListG[c * K + pass] = (unsigned short)br;
    }
}

// ---------------------------------------------------------------------------
// K3 rounds: owner state in REGISTERS (alive, rowHead, rowPtr, colPtr),
// aggregated per-wave atomics, rescan results via rowQans queue.
// ---------------------------------------------------------------------------
__global__ __launch_bounds__(1024) void rounds_fast(const float* __restrict__ C,
                                                    const float* __restrict__ CT,
                                                    const unsigned short* __restrict__ rowListG,
                                                    const unsigned short* __restrict__ colListG,
                                                    int* __restrict__ out,
                                                    int haveCT) {
    __shared__ unsigned short rowList[N * K];   // 32 KB
    __shared__ unsigned short colList[N * K];   // 32 KB
    __shared__ unsigned short colHead[N];       // cross-read in phase 1
    __shared__ unsigned aliveW[N / 32], usedW[N / 32];
    __shared__ unsigned short rowQ[N], colQ[N];
    __shared__ unsigned short rowQans[N];
    __shared__ int rqn, cqn, matched;

    const int t = threadIdx.x;
    const int lane = t & 63;
    const int wave = t >> 6;

    #pragma unroll
    for (int i = 0; i < 2; ++i) {
        ((uint4*)rowList)[i * 1024 + t] = ((const uint4*)rowListG)[i * 1024 + t];
        ((uint4*)colList)[i * 1024 + t] = ((const uint4*)colListG)[i * 1024 + t];
    }
    if (t < N / 32) { aliveW[t] = 0xFFFFFFFFu; usedW[t] = 0u; }
    if (t == 0) { matched = 0; rqn = 0; cqn = 0; }
    __syncthreads();

    // owner-register state
    bool aliveReg = true;
    int rh = rowList[t * K];     // current best unused col of row t
    int rp = 0;                  // index of rh in rowList[t]
    int cp = 0;                  // index of colHead[t] in colList[t]
    int rqIdx = -1;              // pending rescan-queue slot for row t
    colHead[t] = colList[t * K];
    __syncthreads();

    for (int round = 0; round < N + 8; ++round) {
        if (t == 0) { rqn = 0; cqn = 0; }

        // ---- phase 1: pickup rescan result, match mutual-best pairs -------
        if (rqIdx >= 0) { rh = rowQans[rqIdx]; rqIdx = -1; }
        bool didMatch = false;
        if (aliveReg) {
            if ((int)colHead[rh] == t) {
                didMatch = true;
                aliveReg = false;
                out[N + t] = rh;
                atomicOr(&usedW[rh >> 5], 1u << (rh & 31));
            }
        }
        {
            unsigned long long m = __ballot(didMatch);
            if (m) {
                if (lane == 0) {
                    unsigned lo = (unsigned)m;
                    if (lo) atomicAnd(&aliveW[wave << 1], ~lo);
                    atomicAdd(&matched, __popcll(m));
                }
                if (lane == 32) {
                    unsigned hi = (unsigned)(m >> 32);
                    if (hi) atomicAnd(&aliveW[(wave << 1) | 1], ~hi);
                }
            }
        }
        __syncthreads();                                           // B1
        if (matched >= N) break;

        // ---- phase 2a: repair row head (owner registers) ------------------
        if (aliveReg && ((usedW[rh >> 5] >> (rh & 31)) & 1u)) {
            if (rp == SENT) {
                rqIdx = atomicAdd(&rqn, 1); rowQ[rqIdx] = (unsigned short)t;
            } else {
                for (;;) {
                    ++rp;
                    if (rp >= K) { rp = SENT; rqIdx = atomicAdd(&rqn, 1); rowQ[rqIdx] = (unsigned short)t; break; }
                    int c = rowList[t * K + rp];
                    if (!((usedW[c >> 5] >> (c & 31)) & 1u)) { rh = c; break; }
                }
            }
        }
        // ---- phase 2b: repair col head (col t) ----------------------------
        if (!((usedW[t >> 5] >> (t & 31)) & 1u)) {
            int r = colHead[t];
            if (!((aliveW[r >> 5] >> (r & 31)) & 1u)) {
                if (cp == SENT) {
                    int q = atomicAdd(&cqn, 1); colQ[q] = (unsigned short)t;
                } else {
                    for (;;) {
                        ++cp;
                        if (cp >= K) { cp = SENT; int q = atomicAdd(&cqn, 1); colQ[q] = (unsigned short)t; break; }
                        r = colList[t * K + cp];
                        if ((aliveW[r >> 5] >> (r & 31)) & 1u) { colHead[t] = (unsigned short)r; break; }
                    }
                }
            }
        }
        __syncthreads();                                           // B2

        // ---- phase 3: rescans (only when some list exhausted) -------------
        const int nr = rqn, nc = cqn;
        if (nr | nc) {
            const unsigned umU = (usedW[lane >> 1] >> ((lane & 1) << 4)) & 0xFFFFu;
            const unsigned umA = (aliveW[lane >> 1] >> ((lane & 1) << 4)) & 0xFFFFu;

            for (int i = wave; i < nr; i += 16) {          // rows from C
                const int r = rowQ[i];
                const float4* rp4 = (const float4*)(C + (size_t)r * N) + (lane << 2);
                float4 q0 = rp4[0], q1 = rp4[1], q2 = rp4[2], q3 = rp4[3];
                float v[16] = {q0.x, q0.y, q0.z, q0.w, q1.x, q1.y, q1.z, q1.w,
                               q2.x, q2.y, q2.z, q2.w, q3.x, q3.y, q3.z, q3.w};
                float bv = -INFINITY; int bc = N;
                #pragma unroll
                for (int k = 0; k < 16; ++k) {
                    float vv = ((umU >> k) & 1u) ? -INFINITY : v[k];
                    if (vv > bv) { bv = vv; bc = (lane << 4) + k; }
                }
                wave_argmax(bv, bc);
                if (lane == 0) rowQans[i] = (unsigned short)bc;
            }
            if (haveCT) {
                for (int i = wave; i < nc; i += 16) {      // cols from CT
                    const int c = colQ[i];
                    const float4* cp4 = (const float4*)(CT + (size_t)c * N) + (lane << 2);
                    float4 q0 = cp4[0], q1 = cp4[1], q2 = cp4[2], q3 = cp4[3];
                    float v[16] = {q0.x, q0.y, q0.z, q0.w, q1.x, q1.y, q1.z, q1.w,
                                   q2.x, q2.y, q2.z, q2.w, q3.x, q3.y, q3.z, q3.w};
                    float bv = -INFINITY; int br = N;
                    #pragma unroll
                    for (int k = 0; k < 16; ++k) {
                        float vv = ((umA >> k) & 1u) ? v[k] : -INFINITY;
                        if (vv > bv) { bv = vv; br = (lane << 4) + k; }
                    }
                    wave_argmax(bv, br);
                    if (lane == 0) colHead[c] = (unsigned short)br;
                }
            } else {
                for (int i = wave; i < nc; i += 16) {      // cols: strided gather
                    const int c = colQ[i];
                    float bv = -INFINITY; int br = N;
                    #pragma unroll
                    for (int k = 0; k < 16; ++k) {
                        const int r = (k << 6) + lane;
                        bool a = (aliveW[(k << 1) + (lane >> 5)] >> (lane & 31)) & 1u;
                        float vv = a ? C[(size_t)r * N + c] : -INFINITY;
                        if (vv > bv) { bv = vv; br = r; }
                    }
                    wave_argmax(bv, br);
                    if (lane == 0) colHead[c] = (unsigned short)br;
                }
            }
            __syncthreads();                                       // B3
        }
    }

    out[t] = t;   // row-index half: identity
}

// ---------------------------------------------------------------------------
// Fallback (tiny ws): self-contained rounds kernel (alive-list full rescan).
// ---------------------------------------------------------------------------
__device__ __forceinline__ unsigned ordf(unsigned u) {
    return u ^ (unsigned)(((int)u >> 31) | (int)0x80000000);
}
__global__ __launch_bounds__(1024) void rounds_fallback(const float* __restrict__ C,
                                                        int* __restrict__ out) {
    __shared__ unsigned long long ck[N];
    __shared__ unsigned rbc[N];
    __shared__ unsigned short aliveList[2][N];
    __shared__ unsigned colUsedW[N / 32];
    __shared__ int cnts[2];
    const int tid = threadIdx.x;
    const int lane = tid & 63;
    const int wave = tid >> 6;
    aliveList[0][tid] = (unsigned short)tid;
    if (tid < N / 32) colUsedW[tid] = 0u;
    if (tid == 0) { cnts[0] = N; cnts[1] = 0; }
    __syncthreads();
    int p = 0;
    for (int round = 0; round < N + 2; ++round) {
        const int cnt = cnts[p];
        ck[tid] = 0ULL;
        if (tid == 0) cnts[p ^ 1] = 0;
        __syncthreads();
        const unsigned um = (colUsedW[lane >> 1] >> ((lane & 1) << 4)) & 0xFFFFu;
        unsigned cHi[16]; unsigned cRow[16];
        #pragma unroll
        for (int k = 0; k < 16; ++k) { cHi[k] = 0u; cRow[k] = 0u; }
        bool any = false;
        for (int i = wave; i < cnt; i += 16) {
            const int r = aliveList[p][i];
            any = true;
            const float4* rp = (const float4*)(C + (size_t)r * N) + (lane << 2);
            float4 q0 = rp[0], q1 = rp[1], q2 = rp[2], q3 = rp[3];
            float v[16] = {q0.x, q0.y, q0.z, q0.w, q1.x, q1.y, q1.z, q1.w,
                           q2.x, q2.y, q2.z, q2.w, q3.x, q3.y, q3.z, q3.w};
            float bv = -INFINITY; int bc = 0;
            #pragma unroll
            for (int k = 0; k < 16; ++k) {
                unsigned ou = ordf(__float_as_uint(v[k]));
                if (ou > cHi[k] || (ou == cHi[k] && (unsigned)r < cRow[k])) {
                    cHi[k] = ou; cRow[k] = (unsigned)r;
                }
                float vv = ((um >> k) & 1u) ? -INFINITY : v[k];
                if (vv > bv) { bv = vv; bc = (lane << 4) + k; }
            }
            wave_argmax(bv, bc);
            if (lane == 0) rbc[r] = (unsigned)bc;
        }
        if (any) {
            #pragma unroll
            for (int k = 0; k < 16; ++k)
                atomicMax(&ck[(k << 6) | lane],
                          ((unsigned long long)cHi[k] << 32) |
                          (unsigned long long)(N - 1 - cRow[k]));
        }
        __syncthreads();
        if (tid < cnt) {
            const int r = aliveList[p][tid];
            const int c = (int)rbc[r];
            const unsigned long long k64 = ck[((c & 15) << 6) | (c >> 4)];
            const int winner = (N - 1) - (int)(unsigned)(k64 & 0xFFFFFFFFull);
            if (winner == r) {
                out[N + r] = c;
                atomicOr(&colUsedW[c >> 5], 1u << (c & 31));
            } else {
                int idx = atomicAdd(&cnts[p ^ 1], 1);
                aliveList[p ^ 1][idx] = (unsigned short)r;
            }
        }
        __syncthreads();
        p ^= 1;
        if (cnts[p] == 0) break;
    }
    out[tid] = tid;
}

// ---------------------------------------------------------------------------
extern "C" void kernel_launch(void* const* d_in, const int* in_sizes, int n_in,
                              void* d_out, int out_size, void* d_ws, size_t ws_size,
                              hipStream_t stream) {
    const float* C = (const float*)d_in[0];
    int* out = (int*)d_out;

    const size_t listBytes = (size_t)2 * N * K * sizeof(unsigned short);  // 64 KB
    const size_t ctBytes   = (size_t)N * N * sizeof(float);               // 4 MB

    if (ws_size >= listBytes + ctBytes) {
        unsigned short* rowListG = (unsigned short*)d_ws;
        unsigned short* colListG = rowListG + N * K;
        float* CT = (float*)((char*)d_ws + listBytes);
        transpose_k<<<dim3(16, 16), 256, 0, stream>>>(C, CT);
        topk_both<<<512, 256, 0, stream>>>(C, CT, rowListG, colListG);
        rounds_fast<<<1, 1024, 0, stream>>>(C, CT, rowListG, colListG, out, 1);
    } else if (ws_size >= listBytes) {
        unsigned short* rowListG = (unsigned short*)d_ws;
        unsigned short* colListG = rowListG + N * K;
        topk_kernel<<<256, 256, 0, stream>>>(C, rowListG);
        topk_cols<<<64, 1024, 0, stream>>>(C, colListG);
        rounds_fast<<<1, 1024, 0, stream>>>(C, C, rowListG, colListG, out, 0);
    } else {
        rounds_fallback<<<1, 1024, 0, stream>>>(C, out);
    }
}